// Round 18
// baseline (11.362 us; speedup 1.0000x reference)
//
#include <hip/hip_runtime.h>

constexpr int NSTR = 2664;   // sum over wires of 3^|S_w|, S_w = support of R2-pulled Z_w
constexpr int BT   = 256;

struct TabT { unsigned ty[NSTR]; unsigned me[NSTR]; };
struct SlT  { int len[12]; int list[12][6]; };

// R2 = CNOT(w,(w+2)%12), w=0..11 in order. Pull Z_wp back: conjugate w=11..0,
// Z-only rule: z[ctrl] ^= z[tgt].
constexpr SlT build_s() {
    SlT s{};
    for (int wp = 0; wp < 12; ++wp) {
        unsigned z = 1u << wp;
        for (int w = 11; w >= 0; --w) {
            int c = w, tg = (w + 2) % 12;
            if ((z >> tg) & 1u) z ^= 1u << c;
        }
        int ns = 0;
        for (int k = 0; k < 12; ++k) if ((z >> k) & 1u) s.list[wp][ns++] = k;
        s.len[wp] = ns;
        for (int i = ns; i < 6; ++i) s.list[wp][i] = 12;   // pad -> qq[12][*]=1
    }
    return s;
}

// Expand each Z-string through U1 (X/Y/Z choice per support wire), then conjugate
// through R1 = CNOT(w,(w+1)%12) w=0..11 (conjugate w=11..0) with the CHP rule:
//   r ^= x_c z_t (x_t ^ z_c ^ 1);  x_t ^= x_c;  z_c ^= z_t.
constexpr TabT build_tab() {
    TabT t{};
    SlT s = build_s();
    int idx = 0;
    for (int wp = 0; wp < 12; ++wp) {
        int ns = s.len[wp];
        int total = 1;
        for (int i = 0; i < ns; ++i) total *= 3;
        for (int n = 0; n < total; ++n) {
            unsigned xm = 0, zm = 0, choices = 0; int sg = 0, nn = n;
            for (int i = 0; i < ns; ++i) {
                int d = nn % 3; nn /= 3;               // 0=X 1=Y 2=Z
                choices |= (unsigned)d << (2 * i);
                int k = s.list[wp][i];
                if (d == 0 || d == 1) xm |= 1u << k;
                if (d == 1 || d == 2) zm |= 1u << k;
            }
            for (int w = 11; w >= 0; --w) {
                int a = w, b2 = (w + 1) % 12;
                unsigned xa = (xm >> a) & 1u, zb = (zm >> b2) & 1u;
                unsigned xb = (xm >> b2) & 1u, za = (zm >> a) & 1u;
                sg ^= (int)(xa & zb & (xb ^ za ^ 1u));
                xm ^= xa << b2;
                zm ^= zb << a;
            }
            unsigned ty = 0;
            for (int k = 0; k < 12; ++k) {
                unsigned xx = (xm >> k) & 1u, zz = (zm >> k) & 1u;
                unsigned tp = (xx & zz) ? 2u : (xx ? 1u : (zz ? 3u : 0u));
                ty |= tp << (2 * k);
            }
            t.ty[idx] = ty;
            t.me[idx] = (unsigned)wp | ((unsigned)sg << 4) | (choices << 5);
            ++idx;
        }
    }
    return t;
}

__constant__ TabT g_tab = build_tab();
__constant__ SlT  g_sl  = build_s();

__global__ __launch_bounds__(BT)
void qnn_kernel(const float* __restrict__ x, const float* __restrict__ var,
                const float* __restrict__ hw, const float* __restrict__ hb,
                float* __restrict__ out)
{
    // sincos staging: per wire w, slots w*7+{0..6} =
    //   {.5*th0, -.5*(ph0+om0), -.5*(ph0-om0), .5*x, .5*th1, -.5*(ph1+om1), -.5*(ph1-om1)}
    __shared__ float2 sc[84];
    __shared__ float mq[12][4];   // per-wire <v|P|v>, P in {I,X,Y,Z}; sample-dep
    __shared__ float qq[13][4];   // per-wire (.,a,b,c) of B = U1^dag Z U1; row 12 = 1-pad
    __shared__ float hh[12];
    __shared__ float wavesum[4];

    const int t = threadIdx.x, b = blockIdx.x;
    const int lane = t & 63, wid = t >> 6;

    // ---- phase 1: 84 parallel sincosf (depth 1, was depth 4) ----
    if (t < 84) {
        const int w = t / 7, r = t - w * 7;
        float ang;
        if (r == 3) ang = 0.5f * x[b*12 + w];
        else {
            const int g = (r < 3) ? w : 12 + w;           // layer 0 or 1
            const int rr = (r < 3) ? r : r - 4;
            const float phi = var[g*3+0], theta = var[g*3+1], omega = var[g*3+2];
            ang = (rr == 0) ? 0.5f * theta
                : (rr == 1) ? -0.5f * (phi + omega)
                            : -0.5f * (phi - omega);
        }
        float s_, c_; sincosf(ang, &s_, &c_);
        sc[t] = make_float2(s_, c_);
    }
    __syncthreads();

    // ---- phase 2: assemble mq (wave 0) and qq (wave 1) ----
    if (wid == 0 && lane < 12) {
        const int w = lane;
        const float st = sc[w*7+0].x, ct = sc[w*7+0].y;
        const float sp = sc[w*7+1].x, cp = sc[w*7+1].y;
        const float sm = sc[w*7+2].x, cm = sc[w*7+2].y;
        const float s_ = sc[w*7+3].x, c_ = sc[w*7+3].y;
        const float v0r = cp*ct*c_ - cm*st*s_;
        const float v0i = sp*ct*c_ + sm*st*s_;
        const float v1r = cm*st*c_ + cp*ct*s_;
        const float v1i = sm*st*c_ - sp*ct*s_;
        mq[w][0] = 1.0f;
        mq[w][1] = 2.0f*(v0r*v1r + v0i*v1i);                   // <X>
        mq[w][2] = 2.0f*(v0r*v1i - v0i*v1r);                   // <Y>
        mq[w][3] = (v0r*v0r + v0i*v0i) - (v1r*v1r + v1i*v1i);  // <Z>
        hh[w] = hw[w];
    } else if (wid == 1 && lane < 13) {
        if (lane < 12) {
            const int w = lane;
            const float st = sc[w*7+4].x, ct = sc[w*7+4].y;
            const float sp = sc[w*7+5].x, cp = sc[w*7+5].y;
            const float sm = sc[w*7+6].x, cm = sc[w*7+6].y;
            const float u00r =  cp*ct, u00i =  sp*ct;
            const float u01r = -cm*st, u01i =  sm*st;
            const float u10r =  cm*st, u10i =  sm*st;
            const float u11r =  cp*ct, u11i = -sp*ct;
            const float B01r = (u00r*u01r + u00i*u01i) - (u10r*u11r + u10i*u11i);
            const float B01i = (u00r*u01i - u00i*u01r) - (u10r*u11i - u10i*u11r);
            qq[w][0] = 1.0f;
            qq[w][1] = B01r;                                         // a (X)
            qq[w][2] = -B01i;                                        // b (Y)
            qq[w][3] = (u00r*u00r + u00i*u00i) - (u10r*u10r + u10i*u10i);  // c (Z)
        } else {
            qq[12][0] = qq[12][1] = qq[12][2] = qq[12][3] = 1.0f;    // pad row
        }
    }
    __syncthreads();

    // ---- E = hb + sum_strings (+-) h[wp] (prod q over S choices) (prod m over types) ----
    float acc = 0.0f;
    for (int i = t; i < NSTR; i += BT) {
        const unsigned ty = g_tab.ty[i];
        const unsigned me = g_tab.me[i];
        const int wp = me & 15;
        const unsigned ch = me >> 5;
        float cf = hh[wp];
        #pragma unroll
        for (int ii = 0; ii < 6; ++ii) {
            const int k = g_sl.list[wp][ii];     // pads to 12 -> qq[12][*] = 1
            const int d = (ch >> (2*ii)) & 3;
            cf *= qq[k][d + 1];
        }
        if ((me >> 4) & 1) cf = -cf;
        #pragma unroll
        for (int k = 0; k < 12; ++k)
            cf *= mq[k][(ty >> (2*k)) & 3];      // type 0 = I -> *1
        acc += cf;
    }

    #pragma unroll
    for (int off = 32; off > 0; off >>= 1) acc += __shfl_down(acc, off, 64);
    if (lane == 0) wavesum[wid] = acc;
    __syncthreads();
    if (t == 0)
        out[b] = wavesum[0] + wavesum[1] + wavesum[2] + wavesum[3] + hb[0];
}

extern "C" void kernel_launch(void* const* d_in, const int* in_sizes, int n_in,
                              void* d_out, int out_size, void* d_ws, size_t ws_size,
                              hipStream_t stream) {
    const float* x   = (const float*)d_in[0];
    const float* var = (const float*)d_in[1];
    const float* hw  = (const float*)d_in[2];
    const float* hb  = (const float*)d_in[3];
    float* out = (float*)d_out;
    qnn_kernel<<<out_size, BT, 0, stream>>>(x, var, hw, hb, out);
}

// Round 19
// 10.297 us; speedup vs baseline: 1.1034x; 1.1034x over previous
//
#include <hip/hip_runtime.h>

constexpr int NSTR = 2664;   // sum over wires of 3^|S_w|, S_w = support of R2-pulled Z_w
constexpr int BT   = 512;

struct TabT { unsigned ty[NSTR]; unsigned me[NSTR]; };
struct SlT  { int len[12]; int list[12][6]; };

// R2 = CNOT(w,(w+2)%12), w=0..11 in order. Pull Z_wp back: conjugate w=11..0,
// Z-only rule: z[ctrl] ^= z[tgt].
constexpr SlT build_s() {
    SlT s{};
    for (int wp = 0; wp < 12; ++wp) {
        unsigned z = 1u << wp;
        for (int w = 11; w >= 0; --w) {
            int c = w, tg = (w + 2) % 12;
            if ((z >> tg) & 1u) z ^= 1u << c;
        }
        int ns = 0;
        for (int k = 0; k < 12; ++k) if ((z >> k) & 1u) s.list[wp][ns++] = k;
        s.len[wp] = ns;
        for (int i = ns; i < 6; ++i) s.list[wp][i] = 12;   // pad -> qq[12][*]=1
    }
    return s;
}

// Expand each Z-string through U1 (X/Y/Z choice per support wire), then conjugate
// through R1 = CNOT(w,(w+1)%12) w=0..11 (conjugate w=11..0) with the CHP rule:
//   r ^= x_c z_t (x_t ^ z_c ^ 1);  x_t ^= x_c;  z_c ^= z_t.
constexpr TabT build_tab() {
    TabT t{};
    SlT s = build_s();
    int idx = 0;
    for (int wp = 0; wp < 12; ++wp) {
        int ns = s.len[wp];
        int total = 1;
        for (int i = 0; i < ns; ++i) total *= 3;
        for (int n = 0; n < total; ++n) {
            unsigned xm = 0, zm = 0, choices = 0; int sg = 0, nn = n;
            for (int i = 0; i < ns; ++i) {
                int d = nn % 3; nn /= 3;               // 0=X 1=Y 2=Z
                choices |= (unsigned)d << (2 * i);
                int k = s.list[wp][i];
                if (d == 0 || d == 1) xm |= 1u << k;
                if (d == 1 || d == 2) zm |= 1u << k;
            }
            for (int w = 11; w >= 0; --w) {
                int a = w, b2 = (w + 1) % 12;
                unsigned xa = (xm >> a) & 1u, zb = (zm >> b2) & 1u;
                unsigned xb = (xm >> b2) & 1u, za = (zm >> a) & 1u;
                sg ^= (int)(xa & zb & (xb ^ za ^ 1u));
                xm ^= xa << b2;
                zm ^= zb << a;
            }
            unsigned ty = 0;
            for (int k = 0; k < 12; ++k) {
                unsigned xx = (xm >> k) & 1u, zz = (zm >> k) & 1u;
                unsigned tp = (xx & zz) ? 2u : (xx ? 1u : (zz ? 3u : 0u));
                ty |= tp << (2 * k);
            }
            t.ty[idx] = ty;
            t.me[idx] = (unsigned)wp | ((unsigned)sg << 4) | (choices << 5);
            ++idx;
        }
    }
    return t;
}

__constant__ TabT g_tab = build_tab();
__constant__ SlT  g_sl  = build_s();

__global__ __launch_bounds__(BT)
void qnn_kernel(const float* __restrict__ x, const float* __restrict__ var,
                const float* __restrict__ hw, const float* __restrict__ hb,
                float* __restrict__ out)
{
    // sincos staging: per wire w, slots w*7+{0..6} =
    //   {.5*th0, -.5*(ph0+om0), -.5*(ph0-om0), .5*x, .5*th1, -.5*(ph1+om1), -.5*(ph1-om1)}
    __shared__ float2 sc[84];
    __shared__ float mq[12][4];   // per-wire <v|P|v>, P in {I,X,Y,Z}; sample-dep
    __shared__ float qq[13][4];   // per-wire (.,a,b,c) of B = U1^dag Z U1; row 12 = 1-pad
    __shared__ float hh[12];
    __shared__ float wavesum[8];

    const int t = threadIdx.x, b = blockIdx.x;
    const int lane = t & 63, wid = t >> 6;

    // ---- phase 1: 84 parallel sincosf (depth 1, was depth 4 in R17) ----
    if (t < 84) {
        const int w = t / 7, r = t - w * 7;
        float ang;
        if (r == 3) ang = 0.5f * x[b*12 + w];
        else {
            const int g = (r < 3) ? w : 12 + w;           // layer 0 or 1
            const int rr = (r < 3) ? r : r - 4;
            const float phi = var[g*3+0], theta = var[g*3+1], omega = var[g*3+2];
            ang = (rr == 0) ? 0.5f * theta
                : (rr == 1) ? -0.5f * (phi + omega)
                            : -0.5f * (phi - omega);
        }
        float s_, c_; sincosf(ang, &s_, &c_);
        sc[t] = make_float2(s_, c_);
    }
    __syncthreads();

    // ---- phase 2: assemble mq (wave 0) and qq (wave 1) ----
    if (wid == 0 && lane < 12) {
        const int w = lane;
        const float st = sc[w*7+0].x, ct = sc[w*7+0].y;
        const float sp = sc[w*7+1].x, cp = sc[w*7+1].y;
        const float sm = sc[w*7+2].x, cm = sc[w*7+2].y;
        const float s_ = sc[w*7+3].x, c_ = sc[w*7+3].y;
        const float v0r = cp*ct*c_ - cm*st*s_;
        const float v0i = sp*ct*c_ + sm*st*s_;
        const float v1r = cm*st*c_ + cp*ct*s_;
        const float v1i = sm*st*c_ - sp*ct*s_;
        mq[w][0] = 1.0f;
        mq[w][1] = 2.0f*(v0r*v1r + v0i*v1i);                   // <X>
        mq[w][2] = 2.0f*(v0r*v1i - v0i*v1r);                   // <Y>
        mq[w][3] = (v0r*v0r + v0i*v0i) - (v1r*v1r + v1i*v1i);  // <Z>
        hh[w] = hw[w];
    } else if (wid == 1 && lane < 13) {
        if (lane < 12) {
            const int w = lane;
            const float st = sc[w*7+4].x, ct = sc[w*7+4].y;
            const float sp = sc[w*7+5].x, cp = sc[w*7+5].y;
            const float sm = sc[w*7+6].x, cm = sc[w*7+6].y;
            const float u00r =  cp*ct, u00i =  sp*ct;
            const float u01r = -cm*st, u01i =  sm*st;
            const float u10r =  cm*st, u10i =  sm*st;
            const float u11r =  cp*ct, u11i = -sp*ct;
            const float B01r = (u00r*u01r + u00i*u01i) - (u10r*u11r + u10i*u11i);
            const float B01i = (u00r*u01i - u00i*u01r) - (u10r*u11i - u10i*u11r);
            qq[w][0] = 1.0f;
            qq[w][1] = B01r;                                         // a (X)
            qq[w][2] = -B01i;                                        // b (Y)
            qq[w][3] = (u00r*u00r + u00i*u00i) - (u10r*u10r + u10i*u10i);  // c (Z)
        } else {
            qq[12][0] = qq[12][1] = qq[12][2] = qq[12][3] = 1.0f;    // pad row
        }
    }
    __syncthreads();

    // ---- E = hb + sum_strings (+-) h[wp] (prod q over S choices) (prod m over types) ----
    float acc = 0.0f;
    for (int i = t; i < NSTR; i += BT) {
        const unsigned ty = g_tab.ty[i];
        const unsigned me = g_tab.me[i];
        const int wp = me & 15;
        const unsigned ch = me >> 5;
        float cf = hh[wp];
        #pragma unroll
        for (int ii = 0; ii < 6; ++ii) {
            const int k = g_sl.list[wp][ii];     // pads to 12 -> qq[12][*] = 1
            const int d = (ch >> (2*ii)) & 3;
            cf *= qq[k][d + 1];
        }
        if ((me >> 4) & 1) cf = -cf;
        #pragma unroll
        for (int k = 0; k < 12; ++k)
            cf *= mq[k][(ty >> (2*k)) & 3];      // type 0 = I -> *1
        acc += cf;
    }

    #pragma unroll
    for (int off = 32; off > 0; off >>= 1) acc += __shfl_down(acc, off, 64);
    if (lane == 0) wavesum[wid] = acc;
    __syncthreads();
    if (t == 0) {
        float r = hb[0];
        #pragma unroll
        for (int wv = 0; wv < 8; ++wv) r += wavesum[wv];
        out[b] = r;
    }
}

extern "C" void kernel_launch(void* const* d_in, const int* in_sizes, int n_in,
                              void* d_out, int out_size, void* d_ws, size_t ws_size,
                              hipStream_t stream) {
    const float* x   = (const float*)d_in[0];
    const float* var = (const float*)d_in[1];
    const float* hw  = (const float*)d_in[2];
    const float* hb  = (const float*)d_in[3];
    float* out = (float*)d_out;
    qnn_kernel<<<out_size, BT, 0, stream>>>(x, var, hw, hb, out);
}